// Round 5
// baseline (9020.525 us; speedup 1.0000x reference)
//
#include <hip/hip_runtime.h>
#include <stdint.h>
#include <stddef.h>

// Problem constants (test=False shapes)
#define E_DIM 1024
#define B_SZ  16
#define N_SEQ 1024
#define L_NUM 12
#define ACT_D 640   // DIM*ACT_NUM
#define ADIM_ 10

typedef unsigned short u16;
typedef __attribute__((ext_vector_type(8))) short bf16x8;
typedef __attribute__((ext_vector_type(4))) float f32x4;

__device__ __forceinline__ u16 f2bf(float x) {
  union { float f; unsigned int u; } c; c.f = x;
  unsigned int r = c.u + 0x7fffu + ((c.u >> 16) & 1u);
  return (u16)(r >> 16);
}
__device__ __forceinline__ float bf2f(u16 h) {
  union { unsigned int u; float f; } c; c.u = ((unsigned int)h) << 16;
  return c.f;
}

struct us4 { u16 x, y, z, w; };

#define GLD16(gsrc, ldst) __builtin_amdgcn_global_load_lds( \
    (const __attribute__((address_space(1))) void*)(gsrc),  \
    (__attribute__((address_space(3))) void*)(ldst), 16, 0, 0)

// ---------------------------------------------------------------------------
// Error-compensated split-bf16 MFMA NT GEMM — 3-PHASE COUNTED-VMCNT edition.
//   C = A@B^T = Ah@Bh^T + Al@Bh^T + Ah@Bl^T  (fp32 acc)
// R4 post-mortem: 2-phase loop is stage/drain/barrier-path bound (m233);
// fix per m218 = per-phase interleave with counted vmcnt (never 0 in-loop).
// Staging halves: half0={Ah,Bh}, half1={Al,Bl}; per K-step (buf c=t&1):
//  P1: ds_read ah,bh(c) | issue half0(n) | vmcnt(HALF) bar lgkm0 MFMA ah.bh bar
//  P2: ds_read al(c)    | issue half1(n) |             bar lgkm0 MFMA al.bh bar
//  P3: ds_read bl(c)    |               | vmcnt(HALF) bar lgkm0 MFMA ah.bl bar
// vmcnt(HALF)=4 (BN=256) or 3 (BN=128) leaves the newest half in flight;
// vmcnt-then-barrier makes per-wave counts block-wide safe.
// BNT=256: block 256x256, wave 128x64, MA=8. BNT=128: block 256x128,
// wave 64x64, MA=4. BK=32, 2 LDS bufs (128/96 KB), 512 thr / 8 waves.
// XOR k-chunk swizzle ((row>>1)&3, 16B granule) on global source + ds_read
// offset (2-way max conflict = free). m204 bijective XCD swizzle.
// MODE 0: full grid; MODE 1: causal 256r x 128c tiles; MODE 2: K capped at
// (tm+1)*256. EPI 0: Co=acc | 1: split->Ch/Cl | 2: split relu(acc+bias) |
// 3: split causal relu(acc)/(row+1) | 4: Co=acc+bias.
// ---------------------------------------------------------------------------
#define BM 256
#define BK 32

template<int MODE, int EPI, int BNT>
__global__ __launch_bounds__(512)
void gemm_nt_mfma(const u16* __restrict__ Ah, const u16* __restrict__ Al,
                  const u16* __restrict__ Bh0, const u16* __restrict__ Bl0,
                  const u16* __restrict__ Bh1, const u16* __restrict__ Bl1,
                  float* __restrict__ Co,
                  u16* __restrict__ Ch0, u16* __restrict__ Cl0,
                  u16* __restrict__ Ch1, u16* __restrict__ Cl1,
                  const float* __restrict__ bias0, const float* __restrict__ bias1,
                  int K, int lda, int ldb, int ldc, int tilesN,
                  long long sA, long long sB, long long sC)
{
  constexpr int LA = BM * BK;          // 8192 u16 per A operand tile
  constexpr int LB = BNT * BK;         // 8192 / 4096 u16 per B operand tile
  constexpr int BUFU = 2 * LA + 2 * LB;
  __shared__ u16 smem[2 * BUFU];       // 128 KB / 96 KB

  constexpr int WAVE_R = (BNT == 256) ? 128 : 64;
  constexpr int WGC = BNT / 64;        // waves along N: 4 or 2
  constexpr int MA = WAVE_R / 16;      // A frags per wave: 8 or 4

  const int tid = threadIdx.x;
  const int bat = blockIdx.y;

  const u16* Bh = Bh0; const u16* Bl = Bl0;
  u16* Ch = Ch0; u16* Cl = Cl0;
  const float* bias = bias0;
  if (blockIdx.z) { Bh = Bh1; Bl = Bl1; Ch = Ch1; Cl = Cl1; bias = bias1; }

  Ah += bat * sA; Al += bat * sA;
  Bh += bat * sB; Bl += bat * sB;

  // bijective XCD-aware block swizzle (m204); tm-major downstream
  int bid;
  {
    const int nwg = gridDim.x;
    const int q = nwg >> 3, r = nwg & 7;
    const int xcd = blockIdx.x & 7, off = blockIdx.x >> 3;
    bid = ((xcd < r) ? xcd * (q + 1) : r * (q + 1) + (xcd - r) * q) + off;
  }

  int tm, tn;
  if (MODE == 1) {
    // causal 256r x 128c tiles: tn <= 2*tm+1; start(m) = m*(m+1)
    int t = bid, m = 0;
    while ((m + 1) * (m + 2) <= t) m++;
    tm = m; tn = t - m * (m + 1);
  } else {
    tm = bid / tilesN;
    tn = bid % tilesN;
  }
  int kend = K;
  if (MODE == 2) { int c = (tm + 1) * BM; kend = (c < K) ? c : K; }
  const int nk = kend / BK;

  // ---- staging map: A 1024 chunks (2/thread); B: 2/thread (256) or 1 ----
  const int ca0 = tid, ca1 = tid + 512;
  const int ra0 = ca0 >> 2, ra1 = ca1 >> 2;
  const int pa0 = ((ca0 & 3) ^ ((ra0 >> 1) & 3)) * 8;
  const int pa1 = ((ca1 & 3) ^ ((ra1 >> 1) & 3)) * 8;
  const int cb0 = tid, cb1 = tid + 512;
  const int rb0 = cb0 >> 2, rb1 = cb1 >> 2;
  const int pb0 = ((cb0 & 3) ^ ((rb0 >> 1) & 3)) * 8;
  const int pb1 = ((cb1 & 3) ^ ((rb1 >> 1) & 3)) * 8;

  const u16* gAh0 = Ah + (long long)(tm * BM + ra0) * lda + pa0;
  const u16* gAh1 = Ah + (long long)(tm * BM + ra1) * lda + pa1;
  const u16* gAl0 = Al + (long long)(tm * BM + ra0) * lda + pa0;
  const u16* gAl1 = Al + (long long)(tm * BM + ra1) * lda + pa1;
  const u16* gBh0 = Bh + (long long)(tn * BNT + rb0) * ldb + pb0;
  const u16* gBl0 = Bl + (long long)(tn * BNT + rb0) * ldb + pb0;
  const u16* gBh1 = Bh + (long long)(tn * BNT + rb1) * ldb + pb1;
  const u16* gBl1 = Bl + (long long)(tn * BNT + rb1) * ldb + pb1;
  const int oa0 = ca0 * 8, oa1 = ca1 * 8, ob0 = cb0 * 8, ob1 = cb1 * 8;

  // half0 = hi operands (Ah + Bh): 4 GLD (BN=256) or 3 GLD (BN=128)
  auto stage_h0 = [&](int buf) {
    u16* base = smem + buf * BUFU;
    GLD16(gAh0, base + oa0);
    GLD16(gAh1, base + oa1);
    GLD16(gBh0, base + 2 * LA + ob0);
    if (BNT == 256) GLD16(gBh1, base + 2 * LA + ob1);
    gAh0 += BK; gAh1 += BK; gBh0 += BK;
    if (BNT == 256) gBh1 += BK;
  };
  // half1 = lo operands (Al + Bl)
  auto stage_h1 = [&](int buf) {
    u16* base = smem + buf * BUFU;
    GLD16(gAl0, base + LA + oa0);
    GLD16(gAl1, base + LA + oa1);
    GLD16(gBl0, base + 2 * LA + LB + ob0);
    if (BNT == 256) GLD16(gBl1, base + 2 * LA + LB + ob1);
    gAl0 += BK; gAl1 += BK; gBl0 += BK;
    if (BNT == 256) gBl1 += BK;
  };

#define WAIT_HALF() do { if (BNT == 256) asm volatile("s_waitcnt vmcnt(4)" ::: "memory"); \
                         else            asm volatile("s_waitcnt vmcnt(3)" ::: "memory"); } while (0)
#define WAIT_ZERO() asm volatile("s_waitcnt vmcnt(0)" ::: "memory")
#define LGKM0()     asm volatile("s_waitcnt lgkmcnt(0)" ::: "memory")

  // ---- fragment read offsets (u16 units), matching XOR swizzle ----
  const int lane = tid & 63;
  const int w = tid >> 6;
  const int wr = w / WGC, wc = w % WGC;
  const int fr = lane & 15;
  const int kq = (lane >> 4) * 8;
  const int sa = ((fr >> 1) & 3) << 3;                // XOR on u16-idx bits 3..4
  const int aoff = ((wr * WAVE_R + fr) * BK + kq) ^ sa;
  const int boff = ((wc * 64 + fr) * BK + kq) ^ sa;

  f32x4 acc[MA][4];
  #pragma unroll
  for (int m = 0; m < MA; m++)
    #pragma unroll
    for (int n = 0; n < 4; n++) acc[m][n] = (f32x4){0.f, 0.f, 0.f, 0.f};

  // prologue: both halves of buf0 issued; wait half0 (half1 stays in flight)
  stage_h0(0);
  stage_h1(0);
  WAIT_HALF();
  __builtin_amdgcn_s_barrier();

  for (int t = 0; t < nk; t++) {
    const u16* sb = smem + (t & 1) * BUFU;
    const bool pf = (t + 1 < nk);
    const int nb = (t + 1) & 1;

    bf16x8 ah[MA], al[MA], bh[4], bl[4];

    // ---- P1: read ah,bh(cur); issue half0(next); MFMA ah.bh ----
    #pragma unroll
    for (int m = 0; m < MA; m++) ah[m] = *(const bf16x8*)(sb + aoff + m * (16 * BK));
    #pragma unroll
    for (int n = 0; n < 4; n++) bh[n] = *(const bf16x8*)(sb + 2 * LA + boff + n * (16 * BK));
    if (pf) { stage_h0(nb); WAIT_HALF(); } else WAIT_ZERO();   // half1(cur) landed
    __builtin_amdgcn_s_barrier();
    LGKM0();
    __builtin_amdgcn_s_setprio(1);
    #pragma unroll
    for (int m = 0; m < MA; m++)
      #pragma unroll
      for (int n = 0; n < 4; n++)
        acc[m][n] = __builtin_amdgcn_mfma_f32_16x16x32_bf16(ah[m], bh[n], acc[m][n], 0, 0, 0);
    __builtin_amdgcn_s_setprio(0);
    __builtin_amdgcn_s_barrier();

    // ---- P2: read al(cur); issue half1(next); MFMA al.bh ----
    #pragma unroll
    for (int m = 0; m < MA; m++) al[m] = *(const bf16x8*)(sb + LA + aoff + m * (16 * BK));
    if (pf) stage_h1(nb);
    __builtin_amdgcn_s_barrier();
    LGKM0();
    __builtin_amdgcn_s_setprio(1);
    #pragma unroll
    for (int m = 0; m < MA; m++)
      #pragma unroll
      for (int n = 0; n < 4; n++)
        acc[m][n] = __builtin_amdgcn_mfma_f32_16x16x32_bf16(al[m], bh[n], acc[m][n], 0, 0, 0);
    __builtin_amdgcn_s_setprio(0);
    __builtin_amdgcn_s_barrier();

    // ---- P3: read bl(cur); MFMA ah.bl; wait half0(next) ----
    #pragma unroll
    for (int n = 0; n < 4; n++) bl[n] = *(const bf16x8*)(sb + 2 * LA + LB + boff + n * (16 * BK));
    if (pf) WAIT_HALF(); else WAIT_ZERO();                     // half0(next) landed
    __builtin_amdgcn_s_barrier();
    LGKM0();
    __builtin_amdgcn_s_setprio(1);
    #pragma unroll
    for (int m = 0; m < MA; m++)
      #pragma unroll
      for (int n = 0; n < 4; n++)
        acc[m][n] = __builtin_amdgcn_mfma_f32_16x16x32_bf16(ah[m], bl[n], acc[m][n], 0, 0, 0);
    __builtin_amdgcn_s_setprio(0);
    __builtin_amdgcn_s_barrier();
  }

  // epilogue: C/D layout col = lane&15, row = (lane>>4)*4 + reg  [m89/m91]
  if (Co) Co += bat * sC;
  if (Ch) { Ch += bat * sC; Cl += bat * sC; }
  #pragma unroll
  for (int m = 0; m < MA; m++) {
    #pragma unroll
    for (int r = 0; r < 4; r++) {
      const long long row = (long long)tm * BM + wr * WAVE_R + m * 16 + (lane >> 4) * 4 + r;
      #pragma unroll
      for (int n = 0; n < 4; n++) {
        const long long col = (long long)tn * BNT + wc * 64 + n * 16 + (lane & 15);
        float v = acc[m][n][r];
        if (EPI == 2) { v += bias[col]; v = v > 0.f ? v : 0.f; }
        if (EPI == 4) { v += bias[col]; }
        if (EPI == 3) {
          v = v > 0.f ? v : 0.f;
          v = (col <= row) ? v / (float)(row + 1) : 0.f;
        }
        const long long idx = row * (long long)ldc + col;
        if (EPI == 0 || EPI == 4) {
          Co[idx] = v;
        } else {
          u16 h = f2bf(v);
          Ch[idx] = h;
          Cl[idx] = f2bf(v - bf2f(h));
        }
      }
    }
  }
#undef WAIT_HALF
#undef WAIT_ZERO
#undef LGKM0
}

// ---------------------------------------------------------------------------
// Fused weight transposes: up to 3 E x E fp32 -> bf16 hi/lo (dst = src^T)
// ---------------------------------------------------------------------------
struct TP3 {
  const float* s0; const float* s1; const float* s2;
  u16* h0; u16* l0; u16* h1; u16* l1; u16* h2; u16* l2;
};

__global__ __launch_bounds__(256)
void transpose_split3(TP3 p)
{
  __shared__ float tile[32][33];
  const float* src; u16* dh; u16* dl;
  if (blockIdx.z == 0)      { src = p.s0; dh = p.h0; dl = p.l0; }
  else if (blockIdx.z == 1) { src = p.s1; dh = p.h1; dl = p.l1; }
  else                      { src = p.s2; dh = p.h2; dl = p.l2; }
  const int c0 = blockIdx.x * 32, r0 = blockIdx.y * 32;
  const int tx = threadIdx.x & 31, ty = threadIdx.x >> 5;  // 32x8
  #pragma unroll
  for (int i = ty; i < 32; i += 8)
    tile[i][tx] = src[(long long)(r0 + i) * E_DIM + c0 + tx];
  __syncthreads();
  #pragma unroll
  for (int i = ty; i < 32; i += 8) {
    const float v = tile[tx][i];
    const u16 h = f2bf(v);
    const long long idx = (long long)(c0 + i) * E_DIM + r0 + tx;
    dh[idx] = h;
    dl[idx] = f2bf(v - bf2f(h));
  }
}

// ---------------------------------------------------------------------------
// Residual add + LayerNorm on the bf16-pair residual stream:
//   x = (hh+hl) + delta;  (hh,hl) = split(LN(x)*g + b)
// ---------------------------------------------------------------------------
__global__ __launch_bounds__(256)
void resid_ln(u16* __restrict__ hh, u16* __restrict__ hl,
              const float* __restrict__ delta,
              const float* __restrict__ g, const float* __restrict__ bta)
{
  __shared__ float red[8];
  const long long row = blockIdx.x;
  u16* hp = hh + row * E_DIM;
  u16* lp = hl + row * E_DIM;
  const float* dp = delta + row * E_DIM;
  const int tid = threadIdx.x;
  const int e = tid * 4;

  us4 hv = *(const us4*)(hp + e);
  us4 lv = *(const us4*)(lp + e);
  float4 d = *(const float4*)(dp + e);
  float x0 = bf2f(hv.x) + bf2f(lv.x) + d.x;
  float x1 = bf2f(hv.y) + bf2f(lv.y) + d.y;
  float x2 = bf2f(hv.z) + bf2f(lv.z) + d.z;
  float x3 = bf2f(hv.w) + bf2f(lv.w) + d.w;
  float s = x0 + x1 + x2 + x3;
  float q = x0 * x0 + x1 * x1 + x2 * x2 + x3 * x3;
  #pragma unroll
  for (int o = 32; o > 0; o >>= 1) { s += __shfl_down(s, o); q += __shfl_down(q, o); }
  const int lane = tid & 63, wv = tid >> 6;
  if (lane == 0) { red[wv] = s; red[wv + 4] = q; }
  __syncthreads();
  const float st = red[0] + red[1] + red[2] + red[3];
  const float qt = red[4] + red[5] + red[6] + red[7];
  const float mu = st * (1.0f / E_DIM);
  const float var = qt * (1.0f / E_DIM) - mu * mu;
  const float rstd = rsqrtf(var + 1e-5f);

  float4 gg = *(const float4*)(g + e);
  float4 bb = *(const float4*)(bta + e);
  float y0 = (x0 - mu) * rstd * gg.x + bb.x;
  float y1 = (x1 - mu) * rstd * gg.y + bb.y;
  float y2 = (x2 - mu) * rstd * gg.z + bb.z;
  float y3 = (x3 - mu) * rstd * gg.w + bb.w;

  us4 ho, lo;
  ho.x = f2bf(y0); lo.x = f2bf(y0 - bf2f(ho.x));
  ho.y = f2bf(y1); lo.y = f2bf(y1 - bf2f(ho.y));
  ho.z = f2bf(y2); lo.z = f2bf(y2 - bf2f(ho.z));
  ho.w = f2bf(y3); lo.w = f2bf(y3 - bf2f(ho.w));
  *(us4*)(hp + e) = ho;
  *(us4*)(lp + e) = lo;
}

// ---------------------------------------------------------------------------
// Embedding: A_emb[b,e] = act[b,:640] @ W_emb[:640, e]
// ---------------------------------------------------------------------------
__global__ __launch_bounds__(256)
void emb_dot(const float* __restrict__ act, const float* __restrict__ Wemb,
             float* __restrict__ Aemb)
{
  const int e = blockIdx.x * 256 + threadIdx.x;
  const int b = blockIdx.y;
  const float* ab = act + b * ACT_D;
  float s = 0.f;
  for (int d = 0; d < ACT_D; d++)
    s = fmaf(ab[d], Wemb[(long long)d * E_DIM + e], s);
  Aemb[b * E_DIM + e] = s;
}

// Hs[b,i,:] = (i even ? A_emb[b] : 0) + b_emb + W_emb[651] + (i+1)*W_emb[652] + wpe[i]
__global__ __launch_bounds__(256)
void emb_fill(const float* __restrict__ Aemb, const float* __restrict__ Wemb,
              const float* __restrict__ bemb, const float* __restrict__ wpe,
              u16* __restrict__ oh, u16* __restrict__ ol)
{
  const int i = blockIdx.x, b = blockIdx.y;
  const int e = threadIdx.x * 4;
  float4 a;
  if ((i & 1) == 0) a = *(const float4*)(Aemb + b * E_DIM + e);
  else { a.x = 0.f; a.y = 0.f; a.z = 0.f; a.w = 0.f; }
  float4 be = *(const float4*)(bemb + e);
  float4 w1 = *(const float4*)(Wemb + 651LL * E_DIM + e);
  float4 w2 = *(const float4*)(Wemb + 652LL * E_DIM + e);
  float4 pw = *(const float4*)(wpe + (long long)i * E_DIM + e);
  const float pos = (float)(i + 1);
  float y0 = a.x + be.x + w1.x + pos * w2.x + pw.x;
  float y1 = a.y + be.y + w1.y + pos * w2.y + pw.y;
  float y2 = a.z + be.z + w1.z + pos * w2.z + pw.z;
  float y3 = a.w + be.w + w1.w + pos * w2.w + pw.w;
  const long long row = (long long)b * N_SEQ + i;

  us4 ho, lo;
  ho.x = f2bf(y0); lo.x = f2bf(y0 - bf2f(ho.x));
  ho.y = f2bf(y1); lo.y = f2bf(y1 - bf2f(ho.y));
  ho.z = f2bf(y2); lo.z = f2bf(y2 - bf2f(ho.z));
  ho.w = f2bf(y3); lo.w = f2bf(y3 - bf2f(ho.w));
  *(us4*)(oh + row * E_DIM + e) = ho;
  *(us4*)(ol + row * E_DIM + e) = lo;
}

// ---------------------------------------------------------------------------
// Final head: out[b,h,:] = (hh+hl)[b,2h,:] @ W_pred + b_pred
// ---------------------------------------------------------------------------
__global__ __launch_bounds__(256)
void pred_k(const u16* __restrict__ hh, const u16* __restrict__ hl,
            const float* __restrict__ Wp, const float* __restrict__ bp,
            float* __restrict__ out)
{
  __shared__ float part[4][ADIM_];
  const int h = blockIdx.x, b = blockIdx.y;
  const long long row = (long long)b * N_SEQ + 2 * h;
  const u16* xh = hh + row * E_DIM;
  const u16* xl = hl + row * E_DIM;
  float acc[ADIM_];
  #pragma unroll
  for (int a = 0; a < ADIM_; a++) acc[a] = 0.f;
  for (int e = threadIdx.x; e < E_DIM; e += 256) {
    const float xv = bf2f(xh[e]) + bf2f(xl[e]);
    const float* wq = Wp + e * ADIM_;
    #pragma unroll
    for (int a = 0; a < ADIM_; a++) acc[a] = fmaf(xv, wq[a], acc[a]);
  }
  const int lane = threadIdx.x & 63, wv = threadIdx.x >> 6;
  #pragma unroll
  for (int a = 0; a < ADIM_; a++)
    #pragma unroll
    for (int o = 32; o > 0; o >>= 1) acc[a] += __shfl_down(acc[a], o);
  if (lane == 0)
    #pragma unroll
    for (int a = 0; a < ADIM_; a++) part[wv][a] = acc[a];
  __syncthreads();
  if (threadIdx.x < ADIM_) {
    const int a = threadIdx.x;
    out[((long long)b * (N_SEQ / 2) + h) * ADIM_ + a] =
        part[0][a] + part[1][a] + part[2][a] + part[3][a] + bp[a];
  }
}

// Diagnostic sentinel: unambiguous "workspace too small" signature
__global__ __launch_bounds__(256)
void fill_sentinel(float* p, int n, float v)
{
  int i = blockIdx.x * 256 + threadIdx.x;
  if (i < n) p[i] = v;
}

// ---------------------------------------------------------------------------
extern "C" void kernel_launch(void* const* d_in, const int* in_sizes, int n_in,
                              void* d_out, int out_size, void* d_ws, size_t ws_size,
                              hipStream_t stream)
{
  const float* act  = (const float*)d_in[0];
  // d_in[1] context_rewards: numerically unused by the reference
  const float* wpe  = (const float*)d_in[2];
  const float* Wemb = (const float*)d_in[3];
  const float* bemb = (const float*)d_in[4];
  const float* Wq   = (const float*)d_in[5];
  const float* Wk   = (const float*)d_in[6];
  const float* Wv   = (const float*)d_in[7];
  const float* ln1g = (const float*)d_in[8];
  const float* ln1b = (const float*)d_in[9];
  const float* W1   = (const float*)d_in[10];
  const float* b1   = (const float*)d_in[11];
  const float* W2   = (const float*)d_in[12];
  const float* b2   = (const float*)d_in[13];
  const float* ln2g = (const float*)d_in[14];
  const float* ln2b = (const float*)d_in[15];
  const float* Wp   = (const float*)d_in[16];
  const float* bp   = (const float*)d_in[17];
  float* out = (float*)d_out;

  const long long sQ = (long long)N_SEQ * E_DIM;   // per-batch elems (= N^2 too)
  const long long sE = (long long)E_DIM * E_DIM;

  auto need = [&](int G) -> size_t {
    return (size_t)G * sQ * 16 + (size_t)sE * 12
         + (size_t)G * E_DIM * 4 + (size_t)(1 << 20);
  };
  int G = 16;
  while (G > 1 && need(G) > ws_size) G >>= 1;
  if (need(G) > ws_size || d_ws == nullptr || G < 8) {
    fill_sentinel<<<dim3((out_size + 255) / 256), 256, 0, stream>>>(out, out_size, 1.0e7f);
    return;
  }

  char* ws = (char*)d_ws;
  size_t off = 0;
  auto alloc = [&](size_t bytes) -> void* {
    void* p = ws + off;
    off += (bytes + 255) & ~(size_t)255;
    return p;
  };
  u16* hsh = (u16*)alloc((size_t)G * sQ * 2);
  u16* hsl = (u16*)alloc((size_t)G * sQ * 2);
  u16* qh  = (u16*)alloc((size_t)G * sQ * 2);   // q -> vT -> MLP hidden
  u16* ql  = (u16*)alloc((size_t)G * sQ * 2);
  char* kreg = (char*)alloc((size_t)G * sQ * 4);  // k pair, later dbuf f32
  u16* kh = (u16*)kreg;
  u16* kl = kh + (size_t)G * sQ;
  float* dbuf = (float*)kreg;
  u16* sh_ = (u16*)alloc((size_t)G * sQ * 2);
  u16* sl_ = (u16*)alloc((size_t)G * sQ * 2);
  u16* wAh = (u16*)alloc((size_t)sE * 2);
  u16* wAl = (u16*)alloc((size_t)sE * 2);
  u16* wBh = (u16*)alloc((size_t)sE * 2);
  u16* wBl = (u16*)alloc((size_t)sE * 2);
  u16* wCh = (u16*)alloc((size_t)sE * 2);
  u16* wCl = (u16*)alloc((size_t)sE * 2);
  float* Aemb = (float*)alloc((size_t)G * E_DIM * 4);

  const bool wide = (G >= 16);          // per-batch GEMMs: BN=256 if machine stays full
  const int triS = 20;                  // causal 256r x 128c tiles per batch

  const dim3 gqk((G * N_SEQ / BM) * (E_DIM / 256), 1, 2);       // QKV, BN=256
  const dim3 gsq(triS, G, 1);                                   // S, BN=128
  const dim3 gm256((G * N_SEQ / BM) * (E_DIM / 256), 1, 1);     // MLP BN=256
  const dim3 gm128((G * N_SEQ / BM) * (E_DIM / 128), 1, 1);     // MLP BN=128
  const dim3 gv256((N_SEQ / BM) * (E_DIM / 256), G, 1);         // vT/SV BN=256
  const dim3 gv128((N_SEQ / BM) * (E_DIM / 128), G, 1);         // vT/SV BN=128

  for (int g0 = 0; g0 < B_SZ; g0 += G) {
    emb_dot<<<dim3(E_DIM / 256, G), 256, 0, stream>>>(act + (long long)g0 * ACT_D, Wemb, Aemb);
    emb_fill<<<dim3(N_SEQ, G), 256, 0, stream>>>(Aemb, Wemb, bemb, wpe, hsh, hsl);

    for (int l = 0; l < L_NUM; l++) {
      const long long wof = (long long)l * sE;
      const long long bof = (long long)l * E_DIM;

      // Wq,Wk -> wA,wB (hi/lo, transposed)
      TP3 t2 = {Wq + wof, Wk + wof, Wq + wof, wAh, wAl, wBh, wBl, wAh, wAl};
      transpose_split3<<<dim3(32, 32, 2), 256, 0, stream>>>(t2);
      // fused q|k = Hs @ {Wq,Wk}^T -> pairs  (BN=256, z=2)
      gemm_nt_mfma<0, 1, 256><<<gqk, 512, 0, stream>>>(hsh, hsl, wAh, wAl, wBh, wBl,
          nullptr, qh, ql, kh, kl, nullptr, nullptr,
          E_DIM, E_DIM, E_DIM, E_DIM, E_DIM / 256, 0, 0, 0);

      // Wv,W1,W2 -> wA,wB,wC
      TP3 t3 = {Wv + wof, W1 + wof, W2 + wof, wAh, wAl, wBh, wBl, wCh, wCl};
      transpose_split3<<<dim3(32, 32, 3), 256, 0, stream>>>(t3);

      // S = relu(q k^T) * causal/(row+1), causal tiles -> pair (BN=128)
      gemm_nt_mfma<1, 3, 128><<<gsq, 512, 0, stream>>>(qh, ql, kh, kl, kh, kl,
          nullptr, sh_, sl_, sh_, sl_, nullptr, nullptr,
          E_DIM, E_DIM, E_DIM, N_SEQ, 0, sQ, sQ, sQ);

      // vT[e][j] = WvT[e][:] . Hs[j][:]  -> q pair (q dead after S)
      if (wide)
        gemm_nt_mfma<0, 1, 256><<<gv256, 512, 0, stream>>>(wAh, wAl, hsh, hsl, hsh, hsl,
            nullptr, qh, ql, qh, ql, nullptr, nullptr,
            E_DIM, E_DIM, E_DIM, N_SEQ, E_DIM / 256, 0, sQ, sQ);
      else
        gemm_nt_mfma<0, 1, 128><<<gv128, 512, 0, stream>>>(wAh, wAl, hsh, hsl, hsh, hsl,
            nullptr, qh, ql, qh, ql, nullptr, nullptr,
            E_DIM, E_DIM, E_DIM, N_SEQ, E_DIM / 128, 0, sQ, sQ);

      // attn delta = S @ v (K capped at diagonal) -> dbuf (over dead k)
      if (wide)
        gemm_nt_mfma<2, 0, 256><<<gv256, 512, 0, stream>>>(sh_, sl_, qh, ql, qh, ql,
            dbuf, nullptr, nullptr, nullptr, nullptr, nullptr, nullptr,
            N_SEQ, N_SEQ, N_SEQ, E_DIM, E_DIM / 256, sQ, sQ, sQ);
      else
        gemm_nt_mfma<2, 0, 128><<<gv128, 512, 0, stream>>>(sh_, sl_, qh, ql, qh, ql,
            dbuf, nullptr, nullptr, nullptr, nullptr, nullptr, nullptr,
            N_SEQ, N_SEQ, N_SEQ, E_DIM, E_DIM / 128, sQ, sQ, sQ);

      // Hs = LN1(Hs + delta)
      resid_ln<<<dim3(G * N_SEQ), 256, 0, stream>>>(hsh, hsl, dbuf,
          ln1g + bof, ln1b + bof);

      // MLP: hidden = relu(Hs@W1^T + b1) -> q pair
      if (wide)
        gemm_nt_mfma<0, 2, 256><<<gm256, 512, 0, stream>>>(hsh, hsl, wBh, wBl, wBh, wBl,
            nullptr, qh, ql, qh, ql, b1 + bof, b1 + bof,
            E_DIM, E_DIM, E_DIM, E_DIM, E_DIM / 256, 0, 0, 0);
      else
        gemm_nt_mfma<0, 2, 128><<<gm128, 512, 0, stream>>>(hsh, hsl, wBh, wBl, wBh, wBl,
            nullptr, qh, ql, qh, ql, b1 + bof, b1 + bof,
            E_DIM, E_DIM, E_DIM, E_DIM, E_DIM / 128, 0, 0, 0);
      // delta = hidden@W2^T + b2 -> dbuf
      if (wide)
        gemm_nt_mfma<0, 4, 256><<<gm256, 512, 0, stream>>>(qh, ql, wCh, wCl, wCh, wCl,
            dbuf, nullptr, nullptr, nullptr, nullptr, b2 + bof, b2 + bof,
            E_DIM, E_DIM, E_DIM, E_DIM, E_DIM / 256, 0, 0, 0);
      else
        gemm_nt_mfma<0, 4, 128><<<gm128, 512, 0, stream>>>(qh, ql, wCh, wCl, wCh, wCl,
            dbuf, nullptr, nullptr, nullptr, nullptr, b2 + bof, b2 + bof,
            E_DIM, E_DIM, E_DIM, E_DIM, E_DIM / 128, 0, 0, 0);

      // Hs = LN2(Hs + delta)
      resid_ln<<<dim3(G * N_SEQ), 256, 0, stream>>>(hsh, hsl, dbuf,
          ln2g + bof, ln2b + bof);
    }

    pred_k<<<dim3(N_SEQ / 2, G), 256, 0, stream>>>(hsh, hsl, Wp, bp,
        out + (long long)g0 * (N_SEQ / 2) * ADIM_);
  }
}

// Round 6
// 8939.370 us; speedup vs baseline: 1.0091x; 1.0091x over previous
//
#include <hip/hip_runtime.h>
#include <stdint.h>
#include <stddef.h>

// Problem constants (test=False shapes)
#define E_DIM 1024
#define B_SZ  16
#define N_SEQ 1024
#define L_NUM 12
#define ACT_D 640   // DIM*ACT_NUM
#define ADIM_ 10

typedef unsigned short u16;
typedef __attribute__((ext_vector_type(8))) short bf16x8;
typedef __attribute__((ext_vector_type(4))) float f32x4;

__device__ __forceinline__ u16 f2bf(float x) {
  union { float f; unsigned int u; } c; c.f = x;
  unsigned int r = c.u + 0x7fffu + ((c.u >> 16) & 1u);
  return (u16)(r >> 16);
}
__device__ __forceinline__ float bf2f(u16 h) {
  union { unsigned int u; float f; } c; c.u = ((unsigned int)h) << 16;
  return c.f;
}

struct us4 { u16 x, y, z, w; };

#define GLD16(gsrc, ldst) __builtin_amdgcn_global_load_lds( \
    (const __attribute__((address_space(1))) void*)(gsrc),  \
    (__attribute__((address_space(3))) void*)(ldst), 16, 0, 0)

// ---------------------------------------------------------------------------
// Error-compensated split-bf16 MFMA NT GEMM — FINE-GRAINED PHASE edition
// (m201/T3+T4 faithful port; r5's coarse 3-phase was m196-null as predicted).
//   C = A@B^T = Ah@Bh^T + Al@Bh^T + Ah@Bl^T  (fp32 acc)
// BNT=256 (block 256x256, 8 waves 2x4, wave 128x64): 6 phases x 16 MFMA
// per K-step; BNT=128 (block 256x128, waves 4x2, wave 64x64): 3 phases x 16.
// Each phase: {ds_read subtile | 1-3 global_load_lds} bar; lgkm0;
// setprio(1); 16 MFMA; setprio(0); bar.  Counted vmcnt (4 / 3) at exactly
// two points per K-step — loads never drain to 0 in-loop (T4):
//   in-flight 8 -> wait(4): prev half landed, next half stays in flight.
// Staging halves: half0={Ah,Bh} (phases A,B), half1={Al,Bl} (phases C,D).
// XOR k-chunk swizzle ((row>>1)&3, 16B granule) on global source + ds_read
// offset (conflict-free, verified r2-r5). m204 bijective XCD bid swizzle.
// MODE 0: full grid; MODE 1: causal 256r x 128c tiles; MODE 2: K capped at
// (tm+1)*256. EPI 0: Co=acc | 1: split->Ch/Cl | 2: split relu(acc+bias) |
// 3: split causal relu(acc)/(row+1) | 4: Co=acc+bias.
// ---------------------------------------------------------------------------
#define BM 256
#define BK 32

template<int MODE, int EPI, int BNT>
__global__ __launch_bounds__(512)
void gemm_nt_mfma(const u16* __restrict__ Ah, const u16* __restrict__ Al,
                  const u16* __restrict__ Bh0, const u16* __restrict__ Bl0,
                  const u16* __restrict__ Bh1, const u16* __restrict__ Bl1,
                  float* __restrict__ Co,
                  u16* __restrict__ Ch0, u16* __restrict__ Cl0,
                  u16* __restrict__ Ch1, u16* __restrict__ Cl1,
                  const float* __restrict__ bias0, const float* __restrict__ bias1,
                  int K, int lda, int ldb, int ldc, int tilesN,
                  long long sA, long long sB, long long sC)
{
  constexpr int LA = BM * BK;          // 8192 u16 per A operand tile
  constexpr int LB = BNT * BK;         // 8192 / 4096 u16 per B operand tile
  constexpr int BUFU = 2 * LA + 2 * LB;
  __shared__ u16 smem[2 * BUFU];       // 128 KB / 96 KB

  constexpr int WAVE_R = (BNT == 256) ? 128 : 64;
  constexpr int WGC = BNT / 64;        // waves along N: 4 or 2
  constexpr int MA = WAVE_R / 16;      // A frags per wave: 8 or 4

  const int tid = threadIdx.x;
  const int bat = blockIdx.y;

  const u16* Bh = Bh0; const u16* Bl = Bl0;
  u16* Ch = Ch0; u16* Cl = Cl0;
  const float* bias = bias0;
  if (blockIdx.z) { Bh = Bh1; Bl = Bl1; Ch = Ch1; Cl = Cl1; bias = bias1; }

  Ah += bat * sA; Al += bat * sA;
  Bh += bat * sB; Bl += bat * sB;

  // bijective XCD-aware block swizzle (m204); tm-major downstream
  int bid;
  {
    const int nwg = gridDim.x;
    const int q = nwg >> 3, r = nwg & 7;
    const int xcd = blockIdx.x & 7, off = blockIdx.x >> 3;
    bid = ((xcd < r) ? xcd * (q + 1) : r * (q + 1) + (xcd - r) * q) + off;
  }

  int tm, tn;
  if (MODE == 1) {
    // causal 256r x 128c tiles: tn <= 2*tm+1; start(m) = m*(m+1)
    int t = bid, m = 0;
    while ((m + 1) * (m + 2) <= t) m++;
    tm = m; tn = t - m * (m + 1);
  } else {
    tm = bid / tilesN;
    tn = bid % tilesN;
  }
  int kend = K;
  if (MODE == 2) { int c = (tm + 1) * BM; kend = (c < K) ? c : K; }
  const int nk = kend / BK;

  // ---- staging map: A 1024 chunks (2/thread); B: 2/thread (256) or 1 ----
  const int ca0 = tid, ca1 = tid + 512;
  const int ra0 = ca0 >> 2, ra1 = ca1 >> 2;
  const int pa0 = ((ca0 & 3) ^ ((ra0 >> 1) & 3)) * 8;
  const int pa1 = ((ca1 & 3) ^ ((ra1 >> 1) & 3)) * 8;
  const int cb0 = tid, cb1 = tid + 512;
  const int rb0 = cb0 >> 2, rb1 = cb1 >> 2;
  const int pb0 = ((cb0 & 3) ^ ((rb0 >> 1) & 3)) * 8;
  const int pb1 = ((cb1 & 3) ^ ((rb1 >> 1) & 3)) * 8;

  const u16* gAh0 = Ah + (long long)(tm * BM + ra0) * lda + pa0;
  const u16* gAh1 = Ah + (long long)(tm * BM + ra1) * lda + pa1;
  const u16* gAl0 = Al + (long long)(tm * BM + ra0) * lda + pa0;
  const u16* gAl1 = Al + (long long)(tm * BM + ra1) * lda + pa1;
  const u16* gBh0 = Bh + (long long)(tn * BNT + rb0) * ldb + pb0;
  const u16* gBl0 = Bl + (long long)(tn * BNT + rb0) * ldb + pb0;
  const u16* gBh1 = Bh + (long long)(tn * BNT + rb1) * ldb + pb1;
  const u16* gBl1 = Bl + (long long)(tn * BNT + rb1) * ldb + pb1;
  const int oa0 = ca0 * 8, oa1 = ca1 * 8, ob0 = cb0 * 8, ob1 = cb1 * 8;

  // micro-stages (each advances its own pointers)
  auto stA_h0 = [&](int buf) {            // 2 GLD: Ah rows
    u16* base = smem + buf * BUFU;
    GLD16(gAh0, base + oa0); GLD16(gAh1, base + oa1);
    gAh0 += BK; gAh1 += BK;
  };
  auto stB_h0 = [&](int buf) {            // 2 GLD (256) / 1 GLD (128): Bh
    u16* base = smem + buf * BUFU;
    GLD16(gBh0, base + 2 * LA + ob0);
    if (BNT == 256) GLD16(gBh1, base + 2 * LA + ob1);
    gBh0 += BK; if (BNT == 256) gBh1 += BK;
  };
  auto stA_h1 = [&](int buf) {            // 2 GLD: Al rows
    u16* base = smem + buf * BUFU;
    GLD16(gAl0, base + LA + oa0); GLD16(gAl1, base + LA + oa1);
    gAl0 += BK; gAl1 += BK;
  };
  auto stB_h1 = [&](int buf) {            // 2 / 1 GLD: Bl
    u16* base = smem + buf * BUFU;
    GLD16(gBl0, base + 2 * LA + LB + ob0);
    if (BNT == 256) GLD16(gBl1, base + 2 * LA + LB + ob1);
    gBl0 += BK; if (BNT == 256) gBl1 += BK;
  };

#define WAIT_HALF() do { if (BNT == 256) asm volatile("s_waitcnt vmcnt(4)" ::: "memory"); \
                         else            asm volatile("s_waitcnt vmcnt(3)" ::: "memory"); } while (0)
#define WAIT_ZERO() asm volatile("s_waitcnt vmcnt(0)" ::: "memory")
#define LGKM0()     asm volatile("s_waitcnt lgkmcnt(0)" ::: "memory")
#define BAR()       __builtin_amdgcn_s_barrier()
#define PRIO1()     __builtin_amdgcn_s_setprio(1)
#define PRIO0()     __builtin_amdgcn_s_setprio(0)

  // ---- fragment read offsets (u16 units), matching XOR swizzle ----
  const int lane = tid & 63;
  const int w = tid >> 6;
  const int wr = w / WGC, wc = w % WGC;
  const int fr = lane & 15;
  const int kq = (lane >> 4) * 8;
  const int sa = ((fr >> 1) & 3) << 3;                // XOR on u16-idx bits 3..4
  const int aoff = ((wr * WAVE_R + fr) * BK + kq) ^ sa;
  const int boff = ((wc * 64 + fr) * BK + kq) ^ sa;

  f32x4 acc[MA][4];
  #pragma unroll
  for (int m = 0; m < MA; m++)
    #pragma unroll
    for (int n = 0; n < 4; n++) acc[m][n] = (f32x4){0.f, 0.f, 0.f, 0.f};

  // prologue: buf0 fully issued (half0 then half1); wait half0 only
  stA_h0(0); stB_h0(0);
  stA_h1(0); stB_h1(0);
  WAIT_HALF();
  BAR();

  for (int t = 0; t < nk; t++) {
    const u16* sb = smem + (t & 1) * BUFU;
    const bool pf = (t + 1 < nk);
    const int nb = (t + 1) & 1;

    bf16x8 ah[MA], al[MA], bh[4], bl[4];

    if (BNT == 256) {
      // ---- phase A: read ah[0:4],bh[0:4]; GLD Ah(next); MFMA ah03.bh ----
      #pragma unroll
      for (int m = 0; m < 4; m++) ah[m] = *(const bf16x8*)(sb + aoff + m * 512);
      #pragma unroll
      for (int n = 0; n < 4; n++) bh[n] = *(const bf16x8*)(sb + 2 * LA + boff + n * 512);
      if (pf) stA_h0(nb);
      BAR(); LGKM0(); PRIO1();
      #pragma unroll
      for (int m = 0; m < 4; m++)
        #pragma unroll
        for (int n = 0; n < 4; n++)
          acc[m][n] = __builtin_amdgcn_mfma_f32_16x16x32_bf16(ah[m], bh[n], acc[m][n], 0, 0, 0);
      PRIO0(); BAR();

      // ---- phase B: read ah[4:8]; GLD Bh(next); MFMA ah47.bh ----
      #pragma unroll
      for (int m = 4; m < 8; m++) ah[m] = *(const bf16x8*)(sb + aoff + m * 512);
      if (pf) stB_h0(nb);
      BAR(); LGKM0(); PRIO1();
      #pragma unroll
      for (int m = 4; m < 8; m++)
        #pragma unroll
        for (int n = 0; n < 4; n++)
          acc[m][n] = __builtin_amdgcn_mfma_f32_16x16x32_bf16(ah[m], bh[n], acc[m][n], 0, 0, 0);
      PRIO0(); BAR();

      // ---- phase C: vmcnt(4) [half1(cur) landed]; read al[0:4]; GLD Al ----
      if (pf) WAIT_HALF(); else WAIT_ZERO();
      #pragma unroll
      for (int m = 0; m < 4; m++) al[m] = *(const bf16x8*)(sb + LA + aoff + m * 512);
      if (pf) stA_h1(nb);
      BAR(); LGKM0(); PRIO1();
      #pragma unroll
      for (int m = 0; m < 4; m++)
        #pragma unroll
        for (int n = 0; n < 4; n++)
          acc[m][n] = __builtin_amdgcn_mfma_f32_16x16x32_bf16(al[m], bh[n], acc[m][n], 0, 0, 0);
      PRIO0(); BAR();

      // ---- phase D: read al[4:8]; GLD Bl(next); MFMA al47.bh ----
      #pragma unroll
      for (int m = 4; m < 8; m++) al[m] = *(const bf16x8*)(sb + LA + aoff + m * 512);
      if (pf) stB_h1(nb);
      BAR(); LGKM0(); PRIO1();
      #pragma unroll
      for (int m = 4; m < 8; m++)
        #pragma unroll
        for (int n = 0; n < 4; n++)
          acc[m][n] = __builtin_amdgcn_mfma_f32_16x16x32_bf16(al[m], bh[n], acc[m][n], 0, 0, 0);
      PRIO0(); BAR();

      // ---- phase E: read bl[0:4]; MFMA ah03.bl ----
      #pragma unroll
      for (int n = 0; n < 4; n++) bl[n] = *(const bf16x8*)(sb + 2 * LA + LB + boff + n * 512);
      BAR(); LGKM0(); PRIO1();
      #pragma unroll
      for (int m = 0; m < 4; m++)
        #pragma unroll
        for (int n = 0; n < 4; n++)
          acc[m][n] = __builtin_amdgcn_mfma_f32_16x16x32_bf16(ah[m], bl[n], acc[m][n], 0, 0, 0);
      PRIO0(); BAR();

      // ---- phase F: vmcnt(4) [half0(next) landed]; MFMA ah47.bl ----
      if (pf) WAIT_HALF();
      BAR(); PRIO1();
      #pragma unroll
      for (int m = 4; m < 8; m++)
        #pragma unroll
        for (int n = 0; n < 4; n++)
          acc[m][n] = __builtin_amdgcn_mfma_f32_16x16x32_bf16(ah[m], bl[n], acc[m][n], 0, 0, 0);
      PRIO0(); BAR();
    } else {
      // ---- phase A: read ah,bh; GLD half0(next) all; MFMA ah.bh ----
      #pragma unroll
      for (int m = 0; m < MA; m++) ah[m] = *(const bf16x8*)(sb + aoff + m * 512);
      #pragma unroll
      for (int n = 0; n < 4; n++) bh[n] = *(const bf16x8*)(sb + 2 * LA + boff + n * 512);
      if (pf) { stA_h0(nb); stB_h0(nb); }
      BAR(); LGKM0(); PRIO1();
      #pragma unroll
      for (int m = 0; m < MA; m++)
        #pragma unroll
        for (int n = 0; n < 4; n++)
          acc[m][n] = __builtin_amdgcn_mfma_f32_16x16x32_bf16(ah[m], bh[n], acc[m][n], 0, 0, 0);
      PRIO0(); BAR();

      // ---- phase B: vmcnt [half1(cur) landed]; read al; GLD half1(next) ----
      if (pf) WAIT_HALF(); else WAIT_ZERO();
      #pragma unroll
      for (int m = 0; m < MA; m++) al[m] = *(const bf16x8*)(sb + LA + aoff + m * 512);
      if (pf) { stA_h1(nb); stB_h1(nb); }
      BAR(); LGKM0(); PRIO1();
      #pragma unroll
      for (int m = 0; m < MA; m++)
        #pragma unroll
        for (int n = 0; n < 4; n++)
          acc[m][n] = __builtin_amdgcn_mfma_f32_16x16x32_bf16(al[m], bh[n], acc[m][n], 0, 0, 0);
      PRIO0(); BAR();

      // ---- phase C: read bl; vmcnt [half0(next) landed]; MFMA ah.bl ----
      #pragma unroll
      for (int n = 0; n < 4; n++) bl[n] = *(const bf16x8*)(sb + 2 * LA + LB + boff + n * 512);
      if (pf) WAIT_HALF();
      BAR(); LGKM0(); PRIO1();
      #pragma unroll
      for (int m = 0; m < MA; m++)
        #pragma unroll
        for (int n = 0; n < 4; n++)
          acc[m][n] = __builtin_amdgcn_mfma_f32_16x16x32_bf16(ah[m], bl[n], acc[m][n], 0, 0, 0);
      PRIO0(); BAR();
    }
  }

  // epilogue: C/D layout col = lane&15, row = (lane>>4)*4 + reg  [m89/m91]
  if (Co) Co += bat * sC;
  if (Ch) { Ch += bat * sC; Cl += bat * sC; }
  #pragma unroll
  for (int m = 0; m < MA; m++) {
    #pragma unroll
    for (int r = 0; r < 4; r++) {
      const long long row = (long long)tm * BM + wr * WAVE_R + m * 16 + (lane >> 4) * 4 + r;
      #pragma unroll
      for (int n = 0; n < 4; n++) {
        const long long col = (long long)tn * BNT + wc * 64 + n * 16 + (lane & 15);
        float v = acc[m][n][r];
        if (EPI == 2) { v += bias[col]; v = v > 0.f ? v : 0.f; }
        if (EPI == 4) { v += bias[col]; }
        if (EPI == 3) {
          v = v > 0.f ? v : 0.f;
          v = (col <= row) ? v / (float)(row + 1) : 0.f;
        }
        const long long idx = row * (long long)ldc + col;
        if (EPI == 0 || EPI == 4) {
          Co[idx] = v;
        } else {
          u16 h = f2bf(v);
          Ch[idx] = h;
          Cl[idx] = f2bf(v - bf2f(h));
        }
      }
    }
  }
#undef WAIT_HALF
#undef WAIT_ZERO
#undef LGKM0
#undef BAR
#undef PRIO1
#undef PRIO0
}

// ---------------------------------------------------------------------------
// Fused weight transposes: up to 3 E x E fp32 -> bf16 hi/lo (dst = src^T)
// ---------------------------------------------------------------------------
struct TP3 {
  const float* s0; const float* s1; const float* s2;
  u16* h0; u16* l0; u16* h1; u16* l1; u16* h2; u16* l2;
};

__global__ __launch_bounds__(256)
void transpose_split3(TP3 p)
{
  __shared__ float tile[32][33];
  const float* src; u16* dh; u16* dl;
  if (blockIdx.z == 0)      { src = p.s0; dh = p.h0; dl = p.l0; }
  else if (blockIdx.z == 1) { src = p.s1; dh = p.h1; dl = p.l1; }
  else                      { src = p.s2; dh = p.h2; dl = p.l2; }
  const int c0 = blockIdx.x * 32, r0 = blockIdx.y * 32;
  const int tx = threadIdx.x & 31, ty = threadIdx.x >> 5;  // 32x8
  #pragma unroll
  for (int i = ty; i < 32; i += 8)
    tile[i][tx] = src[(long long)(r0 + i) * E_DIM + c0 + tx];
  __syncthreads();
  #pragma unroll
  for (int i = ty; i < 32; i += 8) {
    const float v = tile[tx][i];
    const u16 h = f2bf(v);
    const long long idx = (long long)(c0 + i) * E_DIM + r0 + tx;
    dh[idx] = h;
    dl[idx] = f2bf(v - bf2f(h));
  }
}

// ---------------------------------------------------------------------------
// Residual add + LayerNorm on the bf16-pair residual stream:
//   x = (hh+hl) + delta;  (hh,hl) = split(LN(x)*g + b)
// ---------------------------------------------------------------------------
__global__ __launch_bounds__(256)
void resid_ln(u16* __restrict__ hh, u16* __restrict__ hl,
              const float* __restrict__ delta,
              const float* __restrict__ g, const float* __restrict__ bta)
{
  __shared__ float red[8];
  const long long row = blockIdx.x;
  u16* hp = hh + row * E_DIM;
  u16* lp = hl + row * E_DIM;
  const float* dp = delta + row * E_DIM;
  const int tid = threadIdx.x;
  const int e = tid * 4;

  us4 hv = *(const us4*)(hp + e);
  us4 lv = *(const us4*)(lp + e);
  float4 d = *(const float4*)(dp + e);
  float x0 = bf2f(hv.x) + bf2f(lv.x) + d.x;
  float x1 = bf2f(hv.y) + bf2f(lv.y) + d.y;
  float x2 = bf2f(hv.z) + bf2f(lv.z) + d.z;
  float x3 = bf2f(hv.w) + bf2f(lv.w) + d.w;
  float s = x0 + x1 + x2 + x3;
  float q = x0 * x0 + x1 * x1 + x2 * x2 + x3 * x3;
  #pragma unroll
  for (int o = 32; o > 0; o >>= 1) { s += __shfl_down(s, o); q += __shfl_down(q, o); }
  const int lane = tid & 63, wv = tid >> 6;
  if (lane == 0) { red[wv] = s; red[wv + 4] = q; }
  __syncthreads();
  const float st = red[0] + red[1] + red[2] + red[3];
  const float qt = red[4] + red[5] + red[6] + red[7];
  const float mu = st * (1.0f / E_DIM);
  const float var = qt * (1.0f / E_DIM) - mu * mu;
  const float rstd = rsqrtf(var + 1e-5f);

  float4 gg = *(const float4*)(g + e);
  float4 bb = *(const float4*)(bta + e);
  float y0 = (x0 - mu) * rstd * gg.x + bb.x;
  float y1 = (x1 - mu) * rstd * gg.y + bb.y;
  float y2 = (x2 - mu) * rstd * gg.z + bb.z;
  float y3 = (x3 - mu) * rstd * gg.w + bb.w;

  us4 ho, lo;
  ho.x = f2bf(y0); lo.x = f2bf(y0 - bf2f(ho.x));
  ho.y = f2bf(y1); lo.y = f2bf(y1 - bf2f(ho.y));
  ho.z = f2bf(y2); lo.z = f2bf(y2 - bf2f(ho.z));
  ho.w = f2bf(y3); lo.w = f2bf(y3 - bf2f(ho.w));
  *(us4*)(hp + e) = ho;
  *(us4*)(lp + e) = lo;
}

// ---------------------------------------------------------------------------
// Embedding: A_emb[b,e] = act[b,:640] @ W_emb[:640, e]
// ---------------------------------------------------------------------------
__global__ __launch_bounds__(256)
void emb_dot(const float* __restrict__ act, const float* __restrict__ Wemb,
             float* __restrict__ Aemb)
{
  const int e = blockIdx.x * 256 + threadIdx.x;
  const int b = blockIdx.y;
  const float* ab = act + b * ACT_D;
  float s = 0.f;
  for (int d = 0; d < ACT_D; d++)
    s = fmaf(ab[d], Wemb[(long long)d * E_DIM + e], s);
  Aemb[b * E_DIM + e] = s;
}

// Hs[b,i,:] = (i even ? A_emb[b] : 0) + b_emb + W_emb[651] + (i+1)*W_emb[652] + wpe[i]
__global__ __launch_bounds__(256)
void emb_fill(const float* __restrict__ Aemb, const float* __restrict__ Wemb,
              const float* __restrict__ bemb, const float* __restrict__ wpe,
              u16* __restrict__ oh, u16* __restrict__ ol)
{
  const int i = blockIdx.x, b = blockIdx.y;
  const int e = threadIdx.x * 4;
  float4 a;
  if ((i & 1) == 0) a = *(const float4*)(Aemb + b * E_DIM + e);
  else { a.x = 0.f; a.y = 0.f; a.z = 0.f; a.w = 0.f; }
  float4 be = *(const float4*)(bemb + e);
  float4 w1 = *(const float4*)(Wemb + 651LL * E_DIM + e);
  float4 w2 = *(const float4*)(Wemb + 652LL * E_DIM + e);
  float4 pw = *(const float4*)(wpe + (long long)i * E_DIM + e);
  const float pos = (float)(i + 1);
  float y0 = a.x + be.x + w1.x + pos * w2.x + pw.x;
  float y1 = a.y + be.y + w1.y + pos * w2.y + pw.y;
  float y2 = a.z + be.z + w1.z + pos * w2.z + pw.z;
  float y3 = a.w + be.w + w1.w + pos * w2.w + pw.w;
  const long long row = (long long)b * N_SEQ + i;

  us4 ho, lo;
  ho.x = f2bf(y0); lo.x = f2bf(y0 - bf2f(ho.x));
  ho.y = f2bf(y1); lo.y = f2bf(y1 - bf2f(ho.y));
  ho.z = f2bf(y2); lo.z = f2bf(y2 - bf2f(ho.z));
  ho.w = f2bf(y3); lo.w = f2bf(y3 - bf2f(ho.w));
  *(us4*)(oh + row * E_DIM + e) = ho;
  *(us4*)(ol + row * E_DIM + e) = lo;
}

// ---------------------------------------------------------------------------
// Final head: out[b,h,:] = (hh+hl)[b,2h,:] @ W_pred + b_pred
// ---------------------------------------------------------------------------
__global__ __launch_bounds__(256)
void pred_k(const u16* __restrict__ hh, const u16* __restrict__ hl,
            const float* __restrict__ Wp, const float* __restrict__ bp,
            float* __restrict__ out)
{
  __shared__ float part[4][ADIM_];
  const int h = blockIdx.x, b = blockIdx.y;
  const long long row = (long long)b * N_SEQ + 2 * h;
  const u16* xh = hh + row * E_DIM;
  const u16* xl = hl + row * E_DIM;
  float acc[ADIM_];
  #pragma unroll
  for (int a = 0; a < ADIM_; a++) acc[a] = 0.f;
  for (int e = threadIdx.x; e < E_DIM; e += 256) {
    const float xv = bf2f(xh[e]) + bf2f(xl[e]);
    const float* wq = Wp + e * ADIM_;
    #pragma unroll
    for (int a = 0; a < ADIM_; a++) acc[a] = fmaf(xv, wq[a], acc[a]);
  }
  const int lane = threadIdx.x & 63, wv = threadIdx.x >> 6;
  #pragma unroll
  for (int a = 0; a < ADIM_; a++)
    #pragma unroll
    for (int o = 32; o > 0; o >>= 1) acc[a] += __shfl_down(acc[a], o);
  if (lane == 0)
    #pragma unroll
    for (int a = 0; a < ADIM_; a++) part[wv][a] = acc[a];
  __syncthreads();
  if (threadIdx.x < ADIM_) {
    const int a = threadIdx.x;
    out[((long long)b * (N_SEQ / 2) + h) * ADIM_ + a] =
        part[0][a] + part[1][a] + part[2][a] + part[3][a] + bp[a];
  }
}

// Diagnostic sentinel: unambiguous "workspace too small" signature
__global__ __launch_bounds__(256)
void fill_sentinel(float* p, int n, float v)
{
  int i = blockIdx.x * 256 + threadIdx.x;
  if (i < n) p[i] = v;
}

// ---------------------------------------------------------------------------
extern "C" void kernel_launch(void* const* d_in, const int* in_sizes, int n_in,
                              void* d_out, int out_size, void* d_ws, size_t ws_size,
                              hipStream_t stream)
{
  const float* act  = (const float*)d_in[0];
  // d_in[1] context_rewards: numerically unused by the reference
  const float* wpe  = (const float*)d_in[2];
  const float* Wemb = (const float*)d_in[3];
  const float* bemb = (const float*)d_in[4];
  const float* Wq   = (const float*)d_in[5];
  const float* Wk   = (const float*)d_in[6];
  const float* Wv   = (const float*)d_in[7];
  const float* ln1g = (const float*)d_in[8];
  const float* ln1b = (const float*)d_in[9];
  const float* W1   = (const float*)d_in[10];
  const float* b1   = (const float*)d_in[11];
  const float* W2   = (const float*)d_in[12];
  const float* b2   = (const float*)d_in[13];
  const float* ln2g = (const float*)d_in[14];
  const float* ln2b = (const float*)d_in[15];
  const float* Wp   = (const float*)d_in[16];
  const float* bp   = (const float*)d_in[17];
  float* out = (float*)d_out;

  const long long sQ = (long long)N_SEQ * E_DIM;   // per-batch elems (= N^2 too)
  const long long sE = (long long)E_DIM * E_DIM;

  auto need = [&](int G) -> size_t {
    return (size_t)G * sQ * 16 + (size_t)sE * 12
         + (size_t)G * E_DIM * 4 + (size_t)(1 << 20);
  };
  int G = 16;
  while (G > 1 && need(G) > ws_size) G >>= 1;
  if (need(G) > ws_size || d_ws == nullptr || G < 8) {
    fill_sentinel<<<dim3((out_size + 255) / 256), 256, 0, stream>>>(out, out_size, 1.0e7f);
    return;
  }

  char* ws = (char*)d_ws;
  size_t off = 0;
  auto alloc = [&](size_t bytes) -> void* {
    void* p = ws + off;
    off += (bytes + 255) & ~(size_t)255;
    return p;
  };
  u16* hsh = (u16*)alloc((size_t)G * sQ * 2);
  u16* hsl = (u16*)alloc((size_t)G * sQ * 2);
  u16* qh  = (u16*)alloc((size_t)G * sQ * 2);   // q -> vT -> MLP hidden
  u16* ql  = (u16*)alloc((size_t)G * sQ * 2);
  char* kreg = (char*)alloc((size_t)G * sQ * 4);  // k pair, later dbuf f32
  u16* kh = (u16*)kreg;
  u16* kl = kh + (size_t)G * sQ;
  float* dbuf = (float*)kreg;
  u16* sh_ = (u16*)alloc((size_t)G * sQ * 2);
  u16* sl_ = (u16*)alloc((size_t)G * sQ * 2);
  u16* wAh = (u16*)alloc((size_t)sE * 2);
  u16* wAl = (u16*)alloc((size_t)sE * 2);
  u16* wBh = (u16*)alloc((size_t)sE * 2);
  u16* wBl = (u16*)alloc((size_t)sE * 2);
  u16* wCh = (u16*)alloc((size_t)sE * 2);
  u16* wCl = (u16*)alloc((size_t)sE * 2);
  float* Aemb = (float*)alloc((size_t)G * E_DIM * 4);

  const bool wide = (G >= 16);          // per-batch GEMMs: BN=256 if machine stays full
  const int triS = 20;                  // causal 256r x 128c tiles per batch

  const dim3 gqk((G * N_SEQ / BM) * (E_DIM / 256), 1, 2);       // QKV, BN=256
  const dim3 gsq(triS, G, 1);                                   // S, BN=128
  const dim3 gm256((G * N_SEQ / BM) * (E_DIM / 256), 1, 1);     // MLP BN=256
  const dim3 gm128((G * N_SEQ / BM) * (E_DIM / 128), 1, 1);     // MLP BN=128
  const dim3 gv256((N_SEQ / BM) * (E_DIM / 256), G, 1);         // vT/SV BN=256
  const dim3 gv128((N_SEQ / BM) * (E_DIM / 128), G, 1);         // vT/SV BN=128

  for (int g0 = 0; g0 < B_SZ; g0 += G) {
    emb_dot<<<dim3(E_DIM / 256, G), 256, 0, stream>>>(act + (long long)g0 * ACT_D, Wemb, Aemb);
    emb_fill<<<dim3(N_SEQ, G), 256, 0, stream>>>(Aemb, Wemb, bemb, wpe, hsh, hsl);

    for (int l = 0; l < L_NUM; l++) {
      const long long wof = (long long)l * sE;
      const long long bof = (long long)l * E_DIM;

      // Wq,Wk -> wA,wB (hi/lo, transposed)
      TP3 t2 = {Wq + wof, Wk + wof, Wq + wof, wAh, wAl, wBh, wBl, wAh, wAl};
      transpose_split3<<<dim3(32, 32, 2), 256, 0, stream>>>(t2);
      // fused q|k = Hs @ {Wq,Wk}^T -> pairs  (BN=256, z=2)
      gemm_nt_mfma<0, 1, 256><<<gqk, 512, 0, stream>>>(hsh, hsl, wAh, wAl, wBh, wBl,
          nullptr, qh, ql, kh, kl, nullptr, nullptr,
          E_DIM, E_DIM, E_DIM, E_DIM, E_DIM / 256, 0, 0, 0);

      // Wv,W1,W2 -> wA,wB,wC
      TP3 t3 = {Wv + wof, W1 + wof, W2 + wof, wAh, wAl, wBh, wBl, wCh, wCl};
      transpose_split3<<<dim3(32, 32, 3), 256, 0, stream>>>(t3);

      // S = relu(q k^T) * causal/(row+1), causal tiles -> pair (BN=128)
      gemm_nt_mfma<1, 3, 128><<<gsq, 512, 0, stream>>>(qh, ql, kh, kl, kh, kl,
          nullptr, sh_, sl_, sh_, sl_, nullptr, nullptr,
          E_DIM, E_DIM, E_DIM, N_SEQ, 0, sQ, sQ, sQ);

      // vT[e][j] = WvT[e][:] . Hs[j][:]  -> q pair (q dead after S)
      if (wide)
        gemm_nt_mfma<0, 1, 256><<<gv256, 512, 0, stream>>>(wAh, wAl, hsh, hsl, hsh, hsl,
            nullptr, qh, ql, qh, ql, nullptr, nullptr,
            E_DIM, E_DIM, E_DIM, N_SEQ, E_DIM / 256, 0, sQ, sQ);
      else
        gemm_nt_mfma<0, 1, 128><<<gv128, 512, 0, stream>>>(wAh, wAl, hsh, hsl, hsh, hsl,
            nullptr, qh, ql, qh, ql, nullptr, nullptr,
            E_DIM, E_DIM, E_DIM, N_SEQ, E_DIM / 128, 0, sQ, sQ);

      // attn delta = S @ v (K capped at diagonal) -> dbuf (over dead k)
      if (wide)
        gemm_nt_mfma<2, 0, 256><<<gv256, 512, 0, stream>>>(sh_, sl_, qh, ql, qh, ql,
            dbuf, nullptr, nullptr, nullptr, nullptr, nullptr, nullptr,
            N_SEQ, N_SEQ, N_SEQ, E_DIM, E_DIM / 256, sQ, sQ, sQ);
      else
        gemm_nt_mfma<2, 0, 128><<<gv128, 512, 0, stream>>>(sh_, sl_, qh, ql, qh, ql,
            dbuf, nullptr, nullptr, nullptr, nullptr, nullptr, nullptr,
            N_SEQ, N_SEQ, N_SEQ, E_DIM, E_DIM / 128, sQ, sQ, sQ);

      // Hs = LN1(Hs + delta)
      resid_ln<<<dim3(G * N_SEQ), 256, 0, stream>>>(hsh, hsl, dbuf,
          ln1g + bof, ln1b + bof);

      // MLP: hidden = relu(Hs@W1^T + b1) -> q pair
      if (wide)
        gemm_nt_mfma<0, 2, 256><<<gm256, 512, 0, stream>>>(hsh, hsl, wBh, wBl, wBh, wBl,
            nullptr, qh, ql, qh, ql, b1 + bof, b1 + bof,
            E_DIM, E_DIM, E_DIM, E_DIM, E_DIM / 256, 0, 0, 0);
      else
        gemm_nt_mfma<0, 2, 128><<<gm128, 512, 0, stream>>>(hsh, hsl, wBh, wBl, wBh, wBl,
            nullptr, qh, ql, qh, ql, b1 + bof, b1 + bof,
            E_DIM, E_DIM, E_DIM, E_DIM, E_DIM / 128, 0, 0, 0);
      // delta = hidden@W2^T + b2 -> dbuf
      if (wide)
        gemm_nt_mfma<0, 4, 256><<<gm256, 512, 0, stream>>>(qh, ql, wCh, wCl, wCh, wCl,
            dbuf, nullptr, nullptr, nullptr, nullptr, b2 + bof, b2 + bof,
            E_DIM, E_DIM, E_DIM, E_DIM, E_DIM / 256, 0, 0, 0);
      else
        gemm_nt_mfma<0, 4, 128><<<gm128, 512, 0, stream>>>(qh, ql, wCh, wCl, wCh, wCl,
            dbuf, nullptr, nullptr, nullptr, nullptr, b2 + bof, b2 + bof,
            E_DIM, E_DIM, E_DIM, E_DIM, E_DIM / 128, 0, 0, 0);

      // Hs = LN2(Hs + delta)
      resid_ln<<<dim3(G * N_SEQ), 256, 0, stream>>>(hsh, hsl, dbuf,
          ln2g + bof, ln2b + bof);
    }

    pred_k<<<dim3(N_SEQ / 2, G), 256, 0, stream>>>(hsh, hsl, Wp, bp,
        out + (long long)g0 * (N_SEQ / 2) * ADIM_);
  }
}